// Round 7
// baseline (416.140 us; speedup 1.0000x reference)
//
#include <hip/hip_runtime.h>
#include <math.h>

// SincNetLayer1D on MI355X — round 7.
// Round-6: 265us, VALUBusy 66% (=175us issue vs 110us floor) + 34% stall.
// This round: (1) Gauss 3-mult complex accumulate -> 48 FMA/step (was 64),
// taps pre-transformed to (c, d-c, c+d) float4 in prep; (2) 2-step-deep
// prefetch of taps+x to cover ~200cy L2 latency; (3) ring stores (a,b,a+b).
// Per-step ~53 VALU. Issue floor ~95us; target 115-145us.

#define PI_F 3.14159265358979323846f
#define L_LEN 2048
#define F_N   64
#define FSIZE 129
#define FS_F  16000.0f
#define PADL  64
#define PADR  80
#define PROW  (PADL + L_LEN + PADR)   // 2192 float2 per padded batch row
#define TK    132                      // taps padded to 132 k-rows (3 zero rows)

// ---------------- prep: tpad[k][f] = (c, d-c, c+d, 0), c=bp*cos, d=bp*sin ----------------
__global__ void prep_filters(const float* __restrict__ fc,
                             const float* __restrict__ fbw,
                             float4* __restrict__ tpad)
{
    const int f   = blockIdx.x;    // 64 blocks
    const int tid = threadIdx.x;   // 256 threads
    __shared__ float red[256];

    const float band = fbw[f] * FS_F;
    float bp = 0.0f;
    if (tid < FSIZE) {
        float y;
        const int m = tid - 64;
        if (m == 0) {
            y = 1.0f;
        } else {
            const float tr  = (float)abs(m) / FS_F;
            const float arg = 2.0f * PI_F * band * tr;
            y = __sinf(arg) / arg;
        }
        const float nn  = (float)tid * (129.0f / 128.0f);       // linspace(0,129,129)
        const float win = 0.54f - 0.46f * __cosf(2.0f * PI_F * nn / 129.0f);
        bp = y * (2.0f * band) * win;
    }
    red[tid] = fabsf(bp);
    __syncthreads();
    for (int s = 128; s > 0; s >>= 1) {
        if (tid < s) red[tid] = fmaxf(red[tid], red[tid + s]);
        __syncthreads();
    }
    const float inv = 1.0f / (red[0] + 1e-9f);
    if (tid < FSIZE) {
        const float v  = bp * inv;
        const float ph = 2.0f * PI_F * fc[f] * ((float)tid * (129.0f / 128.0f));
        float sn, cs;
        __sincosf(ph, &sn, &cs);
        const float c = v * cs, d = v * sn;
        tpad[tid * F_N + f] = make_float4(c, d - c, c + d, 0.0f);
    } else if (tid < TK) {
        tpad[tid * F_N + f] = make_float4(0.0f, 0.0f, 0.0f, 0.0f);
    }
}

// ---------------- prep: zero-padded input copy ----------------
__global__ void prep_pad(const float* __restrict__ in, float2* __restrict__ pad, int B)
{
    const int idx = blockIdx.x * 256 + threadIdx.x;
    if (idx >= B * PROW) return;
    const int b = idx / PROW;
    const int i = idx - b * PROW;
    const int p = i - PADL;
    float2 v = make_float2(0.0f, 0.0f);
    if (p >= 0 && p < L_LEN) v = reinterpret_cast<const float2*>(in)[b * L_LEN + p];
    pad[idx] = v;
}

// ---------------- main conv ----------------
__global__ __launch_bounds__(256, 3)   // (256,4) spills: round-5 lesson
void sinc_conv(const float2* __restrict__ pad,    // (B, PROW)
               const float4* __restrict__ tpad,   // (TK, 64): (c, d-c, c+d, 0)
               const float* __restrict__ tl,
               const float* __restrict__ st,
               float* __restrict__ out)           // (B, L, 128)
{
    const int tid = threadIdx.x;
    const int wv  = tid >> 6;
    const int f   = tid & 63;
    const int nlb = L_LEN / 64;
    const int b   = blockIdx.x / nlb;
    const int lw  = (blockIdx.x % nlb) * 64 + wv * 16;

    // Gaussian mask via multiplicative recurrence
    const float tlv = tl[f];
    const float stv = st[f];
    const float c_f = (stv + tlv) * 0.5f;
    const float sd  = tlv * (1.0f / 1.665f) + 1e-9f;
    const float rs  = 1.0f / sd;
    const float i2  = 0.5f * rs * rs;
    const float zn  = (floorf(c_f + 0.5f) - c_f) * rs;
    const float minv = 1.0f / (__expf(-0.5f * zn * zn) + 1e-9f);

    const float p0 = (float)(lw - 64);
    float m = __expf(-(p0 - c_f) * (p0 - c_f) * i2) * minv;
    float u = __expf((2.0f * (c_f - p0) - 1.0f) * i2);
    const float d = __expf(-2.0f * i2);

    const float2* xb = pad + (size_t)b * PROW + (PADL + lw - 64);
    const float4* tp = tpad + f;

    // ring slot (position mod 16) holds (a, b, a+b) of masked input
    float wa[16], wb[16], wab[16];
    float k1[16], k2[16], k3[16];
#pragma unroll
    for (int j = 0; j < 16; ++j) {
        const float2 xv = xb[j];
        const float a = xv.x * m, bb = xv.y * m;
        wa[j] = a; wb[j] = bb; wab[j] = a + bb;
        m *= u; u *= d;
        k1[j] = 0.0f; k2[j] = 0.0f; k3[j] = 0.0f;
    }

    const float2* xs = xb + 16;             // xs[k] = position lw-48+k
    float4 t0 = tp[0];                      // taps k=0
    float4 t1 = tp[F_N];                    // taps k=1
    float2 x0 = xs[0];
    float2 x1 = xs[1];

#pragma unroll 1
    for (int k0 = 0; k0 < 8; ++k0) {
#pragma unroll
        for (int kk = 0; kk < 16; ++kk) {
            const int k = (k0 << 4) + kk;
            const float4 tnx = tp[(size_t)(k + 2) * F_N];   // prefetch 2 ahead
            const float2 xnx = xs[k + 2];
#pragma unroll
            for (int j = 0; j < 16; ++j) {
                const int s = (kk + j) & 15;               // static after unroll
                k1[j] = fmaf(wab[s], t0.x, k1[j]);         // c
                k2[j] = fmaf(wa[s],  t0.y, k2[j]);         // d-c
                k3[j] = fmaf(wb[s],  t0.z, k3[j]);         // c+d
            }
            const float a = x0.x * m, bb = x0.y * m;       // insert position lw-48+k
            wa[kk] = a; wb[kk] = bb; wab[kk] = a + bb;     // slot k&15 == kk
            m *= u; u *= d;
            t0 = t1; t1 = tnx; x0 = x1; x1 = xnx;
        }
    }
    // final step k=128: slots s=j, t0 holds taps k=128
#pragma unroll
    for (int j = 0; j < 16; ++j) {
        k1[j] = fmaf(wab[j], t0.x, k1[j]);
        k2[j] = fmaf(wa[j],  t0.y, k2[j]);
        k3[j] = fmaf(wb[j],  t0.z, k3[j]);
    }

    float* ob = out + ((size_t)b * L_LEN + lw) * (2 * F_N);
#pragma unroll
    for (int j = 0; j < 16; ++j) {
        ob[j * (2 * F_N) + f]       = k1[j] - k3[j];   // real
        ob[j * (2 * F_N) + F_N + f] = k1[j] + k2[j];   // imag
    }
}

extern "C" void kernel_launch(void* const* d_in, const int* in_sizes, int n_in,
                              void* d_out, int out_size, void* d_ws, size_t ws_size,
                              hipStream_t stream)
{
    const float* in  = (const float*)d_in[0];   // (B, 2048, 2) fp32
    const float* fc  = (const float*)d_in[1];
    const float* fbw = (const float*)d_in[2];
    const float* tl  = (const float*)d_in[3];
    const float* st  = (const float*)d_in[4];

    const int B = in_sizes[0] / (L_LEN * 2);    // 128

    float4* tpad = (float4*)d_ws;                                   // 132*64*16 = 135,168 B
    float2* pad  = (float2*)((char*)d_ws + (size_t)TK * F_N * 16);  // B*PROW*8 = 2,244,608 B

    prep_filters<<<F_N, 256, 0, stream>>>(fc, fbw, tpad);
    prep_pad<<<(B * PROW + 255) / 256, 256, 0, stream>>>(in, pad, B);
    sinc_conv<<<B * (L_LEN / 64), 256, 0, stream>>>(pad, tpad, tl, st, (float*)d_out);
}

// Round 9
// 350.959 us; speedup vs baseline: 1.1857x; 1.1857x over previous
//
#include <hip/hip_runtime.h>
#include <math.h>

// SincNetLayer1D on MI355X — round 8 (resubmit; broker timeout last round).
// Round-7 lesson: 3-mult trick (+32 VGPR) -> scratch round-trips (WRITE 427MB),
// net loss. Revert to round-6 direct datapath (64 FMA/step, 84 VGPR), add:
//  (1) 2-deep prefetch of taps+x (covers ~200cy L2 latency; +8 VGPR)
//  (2) split tap base pointers so all global imm offsets <= 3584 B
// Round 6 was 265us = 175us VALU issue + 90us stall. Target 190-225us.

#define PI_F 3.14159265358979323846f
#define L_LEN 2048
#define F_N   64
#define FSIZE 129
#define FS_F  16000.0f
#define PADL  64
#define PADR  80
#define PROW  (PADL + L_LEN + PADR)   // 2192 float2 per padded batch row
#define TK    132                      // tap rows padded (129 real + 3 zero)

// ---------------- prep: krki[k][f] = (kr, ki), TK*64 float2 ----------------
__global__ void prep_filters(const float* __restrict__ fc,
                             const float* __restrict__ fbw,
                             float2* __restrict__ krki)
{
    const int f   = blockIdx.x;    // 64 blocks
    const int tid = threadIdx.x;   // 256 threads
    __shared__ float red[256];

    const float band = fbw[f] * FS_F;
    float bp = 0.0f;
    if (tid < FSIZE) {
        float y;
        const int m = tid - 64;
        if (m == 0) {
            y = 1.0f;
        } else {
            const float tr  = (float)abs(m) / FS_F;
            const float arg = 2.0f * PI_F * band * tr;
            y = __sinf(arg) / arg;
        }
        const float nn  = (float)tid * (129.0f / 128.0f);       // linspace(0,129,129)
        const float win = 0.54f - 0.46f * __cosf(2.0f * PI_F * nn / 129.0f);
        bp = y * (2.0f * band) * win;
    }
    red[tid] = fabsf(bp);
    __syncthreads();
    for (int s = 128; s > 0; s >>= 1) {
        if (tid < s) red[tid] = fmaxf(red[tid], red[tid + s]);
        __syncthreads();
    }
    const float inv = 1.0f / (red[0] + 1e-9f);
    if (tid < FSIZE) {
        const float v  = bp * inv;
        const float ph = 2.0f * PI_F * fc[f] * ((float)tid * (129.0f / 128.0f));
        float sn, cs;
        __sincosf(ph, &sn, &cs);
        krki[tid * F_N + f] = make_float2(v * cs, v * sn);
    } else if (tid < TK) {
        krki[tid * F_N + f] = make_float2(0.0f, 0.0f);          // zero pad rows
    }
}

// ---------------- prep: zero-padded input copy ----------------
__global__ void prep_pad(const float* __restrict__ in, float2* __restrict__ pad, int B)
{
    const int idx = blockIdx.x * 256 + threadIdx.x;
    if (idx >= B * PROW) return;
    const int b = idx / PROW;
    const int i = idx - b * PROW;
    const int p = i - PADL;
    float2 v = make_float2(0.0f, 0.0f);
    if (p >= 0 && p < L_LEN) v = reinterpret_cast<const float2*>(in)[b * L_LEN + p];
    pad[idx] = v;
}

// ---------------- main conv ----------------
__global__ __launch_bounds__(256, 3)   // (256,4) hard-caps VGPR=64 -> spills (round 5). Keep 3.
void sinc_conv(const float2* __restrict__ pad,    // (B, PROW)
               const float2* __restrict__ krki,   // (TK, 64)
               const float* __restrict__ tl,
               const float* __restrict__ st,
               float* __restrict__ out)           // (B, L, 128)
{
    const int tid = threadIdx.x;
    const int wv  = tid >> 6;
    const int f   = tid & 63;
    const int nlb = L_LEN / 64;
    const int b   = blockIdx.x / nlb;
    const int lw  = (blockIdx.x % nlb) * 64 + wv * 16;

    // Gaussian mask via multiplicative recurrence m*=u, u*=d (exact telescope)
    const float tlv = tl[f];
    const float stv = st[f];
    const float c_f = (stv + tlv) * 0.5f;
    const float sd  = tlv * (1.0f / 1.665f) + 1e-9f;
    const float rs  = 1.0f / sd;
    const float i2  = 0.5f * rs * rs;
    const float zn  = (floorf(c_f + 0.5f) - c_f) * rs;
    const float minv = 1.0f / (__expf(-0.5f * zn * zn) + 1e-9f);

    const float p0 = (float)(lw - 64);
    float m = __expf(-(p0 - c_f) * (p0 - c_f) * i2) * minv;
    float u = __expf((2.0f * (c_f - p0) - 1.0f) * i2);
    const float d = __expf(-2.0f * i2);

    const float2* xb = pad + (size_t)b * PROW + (PADL + lw - 64);
    const float2* tb = krki + f;

    // ring: slot (position mod 16); lw % 16 == 0 so position lw-64+j -> slot j
    float2 w[16];
    float  ar[16], ai[16];
#pragma unroll
    for (int j = 0; j < 16; ++j) {
        const float2 xv = xb[j];
        w[j] = make_float2(xv.x * m, xv.y * m);
        m *= u; u *= d;
        ar[j] = 0.0f; ai[j] = 0.0f;
    }

    const float2* xs = xb + 16;        // xs[k] = position lw-48+k
    float2 t0 = tb[0];                 // tap row k
    float2 t1 = tb[F_N];               // tap row k+1
    float2 x0 = xs[0];                 // incoming x for step k
    float2 x1 = xs[1];                 // incoming x for step k+1

#pragma unroll 1
    for (int k0 = 0; k0 < 8; ++k0) {
        // two bases so every load's imm offset <= 3584 B (13-bit range is 4095)
        const float2* tkA = tb + (size_t)((k0 << 4) + 2) * F_N;   // rows k+2, kk=0..7
        const float2* tkB = tkA + (size_t)8 * F_N;                // rows k+2, kk=8..15
        const float2* xk  = xs + (k0 << 4) + 2;                   // x two ahead
#pragma unroll
        for (int kk = 0; kk < 16; ++kk) {
            const float2 tnx = (kk < 8) ? tkA[(size_t)kk * F_N]
                                        : tkB[(size_t)(kk - 8) * F_N];  // row k+2
            const float2 xnx = xk[kk];                                   // pos lw-48+k+2
#pragma unroll
            for (int j = 0; j < 16; ++j) {
                const int s = (kk + j) & 15;           // static after unroll
                ar[j] = fmaf(w[s].x,  t0.x, ar[j]);
                ar[j] = fmaf(w[s].y, -t0.y, ar[j]);
                ai[j] = fmaf(w[s].x,  t0.y, ai[j]);
                ai[j] = fmaf(w[s].y,  t0.x, ai[j]);
            }
            w[kk] = make_float2(x0.x * m, x0.y * m);   // insert pos lw-48+k, slot kk
            m *= u; u *= d;
            t0 = t1; t1 = tnx;                         // renamed in unrolled code
            x0 = x1; x1 = xnx;
        }
    }
    // final step k=128: slots s=j, t0 holds tap row 128
#pragma unroll
    for (int j = 0; j < 16; ++j) {
        ar[j] = fmaf(w[j].x,  t0.x, ar[j]);
        ar[j] = fmaf(w[j].y, -t0.y, ar[j]);
        ai[j] = fmaf(w[j].x,  t0.y, ai[j]);
        ai[j] = fmaf(w[j].y,  t0.x, ai[j]);
    }

    float* ob = out + ((size_t)b * L_LEN + lw) * (2 * F_N);
#pragma unroll
    for (int j = 0; j < 16; ++j) {
        ob[j * (2 * F_N) + f]       = ar[j];   // real: channels 0..63
        ob[j * (2 * F_N) + F_N + f] = ai[j];   // imag: channels 64..127
    }
}

extern "C" void kernel_launch(void* const* d_in, const int* in_sizes, int n_in,
                              void* d_out, int out_size, void* d_ws, size_t ws_size,
                              hipStream_t stream)
{
    const float* in  = (const float*)d_in[0];   // (B, 2048, 2) fp32
    const float* fc  = (const float*)d_in[1];
    const float* fbw = (const float*)d_in[2];
    const float* tl  = (const float*)d_in[3];
    const float* st  = (const float*)d_in[4];

    const int B = in_sizes[0] / (L_LEN * 2);    // 128

    float2* krki = (float2*)d_ws;                                   // TK*64*8 = 67,584 B
    float2* pad  = (float2*)((char*)d_ws + (size_t)TK * F_N * 8);   // B*PROW*8 = 2,244,608 B

    prep_filters<<<F_N, 256, 0, stream>>>(fc, fbw, krki);
    prep_pad<<<(B * PROW + 255) / 256, 256, 0, stream>>>(in, pad, B);
    sinc_conv<<<B * (L_LEN / 64), 256, 0, stream>>>(pad, krki, tl, st, (float*)d_out);
}